// Round 10
// baseline (284.095 us; speedup 1.0000x reference)
//
#include <hip/hip_runtime.h>
#include <math.h>

#define G_     128
#define E_     524288
#define EPG    4096
#define DEGMAX 48

typedef __attribute__((ext_vector_type(8))) short bf16x8;
typedef __attribute__((ext_vector_type(4))) float f32x4;
typedef __attribute__((ext_vector_type(4))) unsigned short u16x4;

__device__ inline void split_bf16(float x, short& hi, short& lo){
    unsigned u = __float_as_uint(x);
    hi = (short)(u >> 16);
    float hf = __uint_as_float(u & 0xffff0000u);
    unsigned r = __float_as_uint(x - hf);
    lo = (short)(r >> 16);
}

// y-row XOR swizzle: rows are 32 words (128B) -> every row starts at bank 0 and any
// wave touching 8 rows at the same column 8-way aliases a 4-bank set. XOR the row's
// low 3 bits into the column slot: bijective per row, spreads the 8 rows across all
// bank sets. v=0 (row-0 correction) is unchanged by construction.
__device__ inline int ysw(int v, int f4){ return v*32 + (f4 ^ ((v & 7) << 2)); }

// ================= shared GEMM body: Y = X(Mx128) @ W(128x128) + bias (+score) =================
// smem layout: wsh[0,34816) wsl[34816,69632) bsh[69632,70144) qs[70144,70656) red[70656,70912)
template<int WAVES>
__device__ void gemm_body(char* smem, int bid, const float* __restrict__ X,
        const float* __restrict__ W, const float* __restrict__ bias, float* __restrict__ Y,
        const float* __restrict__ p, const float* __restrict__ beta,
        const int* __restrict__ cntv, float* __restrict__ score){
    short* wsh = (short*)smem;
    short* wsl = (short*)(smem + 34816);
    float* bsh = (float*)(smem + 69632);
    float* qs  = (float*)(smem + 70144);
    float* rednorm = (float*)(smem + 70656);
    const int NT = WAVES*64;
    int t = threadIdx.x;
    for (int e = t; e < 16384; e += NT){
        int k = e >> 7, n = e & 127;
        short hi, lo; split_bf16(W[e], hi, lo);
        wsh[n*136 + k] = hi; wsl[n*136 + k] = lo;
    }
    if (t < 128) bsh[t] = bias[t];
    if (score && t < 64){ float a = p[t], b = p[t+64]; rednorm[t] = a*a + b*b; }
    __syncthreads();
    float b1 = 0.f;
    if (score){
        if (t == 0){ float s = 0.f; for (int i = 0; i < 64; i++) s += rednorm[i]; rednorm[0] = sqrtf(s); }
        __syncthreads();
        if (t < 128) qs[t] = beta[0] * p[t] / rednorm[0];
        b1 = beta[1];
        __syncthreads();
    }
    int wave = t >> 6, lane = t & 63;
    int ln = lane & 15, q = lane >> 4;
    size_t rb = (size_t)bid * (WAVES*16);
    const float* xrow = &X[(rb + wave*16 + ln)*128 + q*8];
    f32x4 acc[8];
    #pragma unroll
    for (int i = 0; i < 8; i++) acc[i] = (f32x4){0.f,0.f,0.f,0.f};
    #pragma unroll
    for (int kc = 0; kc < 4; kc++){
        float4 xa = *(const float4*)(xrow + kc*32);
        float4 xb = *(const float4*)(xrow + kc*32 + 4);
        bf16x8 ah, al; short hi, lo;
        split_bf16(xa.x, hi, lo); ah[0]=hi; al[0]=lo;
        split_bf16(xa.y, hi, lo); ah[1]=hi; al[1]=lo;
        split_bf16(xa.z, hi, lo); ah[2]=hi; al[2]=lo;
        split_bf16(xa.w, hi, lo); ah[3]=hi; al[3]=lo;
        split_bf16(xb.x, hi, lo); ah[4]=hi; al[4]=lo;
        split_bf16(xb.y, hi, lo); ah[5]=hi; al[5]=lo;
        split_bf16(xb.z, hi, lo); ah[6]=hi; al[6]=lo;
        split_bf16(xb.w, hi, lo); ah[7]=hi; al[7]=lo;
        #pragma unroll
        for (int nt = 0; nt < 8; nt++){
            int wo = (nt*16 + ln)*136 + kc*32 + q*8;
            bf16x8 bh = *(const bf16x8*)&wsh[wo];
            bf16x8 bl = *(const bf16x8*)&wsl[wo];
            acc[nt] = __builtin_amdgcn_mfma_f32_16x16x32_bf16(ah, bh, acc[nt], 0, 0, 0);
            acc[nt] = __builtin_amdgcn_mfma_f32_16x16x32_bf16(ah, bl, acc[nt], 0, 0, 0);
            acc[nt] = __builtin_amdgcn_mfma_f32_16x16x32_bf16(al, bh, acc[nt], 0, 0, 0);
        }
    }
    #pragma unroll
    for (int nt = 0; nt < 8; nt++){
        int c = nt*16 + ln;
        float bb = bsh[c];
        #pragma unroll
        for (int r = 0; r < 4; r++){
            Y[(rb + wave*16 + q*4 + r)*128 + c] = acc[nt][r] + bb;
        }
    }
    if (score){
        #pragma unroll
        for (int r = 0; r < 4; r++){
            float sp = 0.f;
            #pragma unroll
            for (int nt = 0; nt < 8; nt++){
                int c = nt*16 + ln;
                sp += (acc[nt][r] + bsh[c]) * qs[c];
            }
            sp += __shfl_xor(sp, 1);
            sp += __shfl_xor(sp, 2);
            sp += __shfl_xor(sp, 4);
            sp += __shfl_xor(sp, 8);
            if (ln == 0){
                int row = (int)rb + wave*16 + q*4 + r;
                score[row] = sp + b1 * (float)cntv[row];
            }
        }
    }
}

// ================= standalone GEMM (+score) =================
template<int WAVES>
__global__ __launch_bounds__(WAVES*64) void k_gemm_mfma(const float* __restrict__ X,
        const float* __restrict__ W, const float* __restrict__ bias, float* __restrict__ Y,
        const float* __restrict__ p, const float* __restrict__ beta,
        const int* __restrict__ cntv, float* __restrict__ score){
    __shared__ __align__(16) char smem[70912];
    gemm_body<WAVES>(smem, blockIdx.x, X, W, bias, Y, p, beta, cntv, score);
}

// ================= stage-1 prep: LDS-built CSR + coalesced writeout + sort + degree-prop =================
// R21 (proven): CSR built in LDS, written to global coalesced, degree-prop reads LDS.
__global__ __launch_bounds__(512) void k_prep1(const int* __restrict__ ei,
        int* __restrict__ cnt, unsigned short* __restrict__ csrcp,
        int* __restrict__ permg, float* __restrict__ dinvg){
    __shared__ int   lcnt[512];
    __shared__ __align__(16) unsigned short csrS[512*DEGMAX + 8];  // 49168 B (+8B prefetch pad)
    __shared__ float y[1024];          // degree ping-pong
    __shared__ int   bins[64];
    __shared__ int   permS[512];
    int g = blockIdx.x, t = threadIdx.x, gbase = g*512;
    lcnt[t] = 0;
    if (t < 64) bins[t] = 0;
    unsigned* c32 = (unsigned*)csrS;
    for (int i = t; i < 512*DEGMAX/2 + 4; i += 512) c32[i] = 0;
    __syncthreads();
    for (int i = t; i < EPG; i += 512){
        int e = g*EPG + i;
        int sv = ei[e] & 511;          // ids are g*512+local; 512-aligned -> &511 = local
        int d  = ei[E_ + e] & 511;
        int slot = atomicAdd(&lcnt[d], 1);
        if (slot < DEGMAX) csrS[d*DEGMAX + slot] = (unsigned short)sv;
    }
    __syncthreads();                   // csrS + lcnt ready
    {   // coalesced CSR writeout (k_prop reads it from global)
        unsigned* dst = (unsigned*)(csrcp + (size_t)gbase*DEGMAX);
        for (int i = t; i < 512*DEGMAX/2; i += 512) dst[i] = c32[i];
    }
    int rawc = lcnt[t];
    cnt[gbase + t] = rawc;             // GEMM score epilogue's node-strength term (unclamped)
    int dc = min(rawc, DEGMAX);
    atomicAdd(&bins[dc], 1);
    __syncthreads();
    if (t < 64){
        int v0 = bins[t], s = v0;
        #pragma unroll
        for (int off = 1; off < 64; off <<= 1){
            int n = __shfl_up(s, off);
            if (t >= off) s += n;
        }
        bins[t] = s - v0;              // exclusive prefix
    }
    __syncthreads();
    {
        int slot = atomicAdd(&bins[dc], 1);
        int pk = t | (dc << 16);
        permS[slot] = pk;
        permg[gbase + slot] = pk;
    }
    __syncthreads();
    int pk = permS[t];
    int pv = pk & 0xffff, pd = pk >> 16;
    y[pv] = 1.f;
    __syncthreads();
    float dacc = 1.f;
    int cur = 0;
    for (int l = 0; l < 4; l++){
        const float* la = &y[cur*512];
        float s = 0.f;
        int nq = (pd + 3) >> 2;
        const u16x4* cp = (const u16x4*)(csrS + pv*DEGMAX);   // LDS
        u16x4 oc = cp[0];
        #pragma unroll 1
        for (int jq = 0; jq < nq; jq++){
            u16x4 ocn = cp[jq + 1];    // +8B over-read lands in csrS pad
            s += (la[(int)oc[0]] + la[(int)oc[1]]) + (la[(int)oc[2]] + la[(int)oc[3]]);
            oc = ocn;
        }
        if (nq) s -= (float)(nq*4 - pd) * la[0];
        y[(1^cur)*512 + pv] = s;
        dacc += s;
        __syncthreads();
        cur ^= 1;
    }
    dinvg[gbase + pv] = rsqrtf(fmaxf(dacc, 1e-12f));
}

// ---------------- per-graph feature prop (R19 form + R22 y-swizzle) ----------------
// OUT = dinv * (sum_l A^l)(dinv * x). R15 tiling (1024 thr, fq=4, 128B row stride).
// R22: ysw() XOR-swizzle on ALL y accesses -> kills the 8-rows-same-bank-set aliasing
// (measured 3.15M conflict-cycles). R20's CSR-LDS staging was neutral-negative ->
// CSR stays global with 1-deep prefetch (TLP hides it).
// REGISTER HISTORY (DO NOT REPEAT): min-waves hints (R7/R14 launch_bounds(1024,8))
// force a 32-VGPR ceiling -> catastrophic scratch spill (FETCH 20->160MB).
template<int NPER, int L, int IT, bool SEL>
__global__ __launch_bounds__(1024)
void k_prop(const int* __restrict__ permg, const float* __restrict__ dinvg,
        const unsigned short* __restrict__ csrcp,
        const float* __restrict__ X, const int* __restrict__ selg,
        const float* __restrict__ thg, float* __restrict__ OUT){
    __shared__ __align__(16) float y[NPER*32];
    __shared__ float dinvs[NPER];
    int g = blockIdx.x, fq = blockIdx.y, gbase = g*NPER;
    int t = threadIdx.x;
    int f4 = (t & 7)*4;
    int fo = fq*32 + f4;
    if (t < NPER) dinvs[t] = dinvg[gbase + t];
    int pkr[IT];
    {
        int wv = t >> 6, gi = (t >> 3) & 7;
        #pragma unroll
        for (int it = 0; it < IT; it++){
            int ch = (it & 1) ? (15 - wv) : wv;
            pkr[it] = permg[gbase + (16*it + ch)*8 + gi];
        }
    }
    __syncthreads();
    float4 acc[IT];
    #pragma unroll
    for (int it = 0; it < IT; it++){
        int v = pkr[it] & 0xffff;
        float d = dinvs[v];
        size_t row;
        if (SEL){
            row = (size_t)selg[gbase + v];
            d *= thg[gbase + v];
        } else {
            row = (size_t)(gbase + v);
        }
        float4 w = *(const float4*)&X[row*128 + fo];
        w.x*=d; w.y*=d; w.z*=d; w.w*=d;
        acc[it] = w;
        *(float4*)&y[ysw(v, f4)] = w;
    }
    __syncthreads();
    for (int l = 0; l < L; l++){
        float4 s[IT];
        #pragma unroll
        for (int it = 0; it < IT; it++){
            int pk = pkr[it];
            int c = pk >> 16;
            int nq = (c + 3) >> 2;
            const u16x4* cp = (const u16x4*)(csrcp + (size_t)(gbase + (pk & 0xffff))*DEGMAX);
            float4 ss = make_float4(0.f,0.f,0.f,0.f);
            u16x4 oc = cp[0];
            #pragma unroll 1
            for (int jq = 0; jq < nq; jq++){
                u16x4 ocn = cp[jq + 1];
                float4 w0 = *(const float4*)&y[ysw((int)oc[0], f4)];
                float4 w1 = *(const float4*)&y[ysw((int)oc[1], f4)];
                float4 w2 = *(const float4*)&y[ysw((int)oc[2], f4)];
                float4 w3 = *(const float4*)&y[ysw((int)oc[3], f4)];
                ss.x += (w0.x + w1.x) + (w2.x + w3.x);
                ss.y += (w0.y + w1.y) + (w2.y + w3.y);
                ss.z += (w0.z + w1.z) + (w2.z + w3.z);
                ss.w += (w0.w + w1.w) + (w2.w + w3.w);
                oc = ocn;
            }
            if (nq){
                float fp = (float)(nq*4 - c);
                float4 z = *(const float4*)&y[f4];          // row 0: ysw(0,f4)==f4 (broadcast)
                ss.x -= fp*z.x; ss.y -= fp*z.y; ss.z -= fp*z.z; ss.w -= fp*z.w;
            }
            s[it] = ss;
        }
        __syncthreads();
        #pragma unroll
        for (int it = 0; it < IT; it++){
            int v = pkr[it] & 0xffff;
            *(float4*)&y[ysw(v, f4)] = s[it];
            acc[it].x+=s[it].x; acc[it].y+=s[it].y; acc[it].z+=s[it].z; acc[it].w+=s[it].w;
        }
        __syncthreads();
    }
    #pragma unroll
    for (int it = 0; it < IT; it++){
        int v = pkr[it] & 0xffff;
        float d = dinvs[v];
        float4 w = acc[it];
        w.x*=d; w.y*=d; w.z*=d; w.w*=d;
        *(float4*)&OUT[(size_t)(gbase + v)*128 + fo] = w;
    }
}

// ---------------- pooling control: rank + sel/th emit + edge remap + next-stage prep ----------------
// R22: next-stage CSR built in LDS (proven R21 pattern: scattered global u16 RMW ->
// LDS stores), coalesced u32 writeout, tail degree-prop reads LDS. Pads stay 0 from
// the LDS memset.
template<int NPER, bool BUILD>
__global__ __launch_bounds__(512) void k_pooltop(const float* __restrict__ score_in,
        const int* __restrict__ esrc_in, const int* __restrict__ edst_in,
        int* __restrict__ esrc_out, int* __restrict__ edst_out,
        int* __restrict__ cnt_next, unsigned short* __restrict__ csrcp,
        int* __restrict__ permg, float* __restrict__ dinvg,
        int* __restrict__ selg, float* __restrict__ thg){
    const int K = NPER/2;
    constexpr int CSRSZ = BUILD ? (NPER/2)*DEGMAX + 8 : 8;
    __shared__ __align__(16) float sc[NPER];
    __shared__ int  nid[NPER];
    __shared__ int  lcnt[NPER/2];
    __shared__ int  bins[64];
    __shared__ int  permS[NPER/2];
    __shared__ __align__(16) unsigned short csrS[CSRSZ];
    int g = blockIdx.x, t = threadIdx.x, gbase = g*NPER;
    if (t < K) lcnt[t] = 0;
    if (t < 64) bins[t] = 0;
    if (BUILD){
        unsigned* c32 = (unsigned*)csrS;
        for (int i = t; i < K*DEGMAX/2 + 4; i += 512) c32[i] = 0;
    }
    if (t < NPER) sc[t] = score_in[gbase + t];
    __syncthreads();
    if (t < NPER){
        float s = sc[t];
        int rank = 0;
        const float4* sc4 = (const float4*)sc;
        #pragma unroll 8
        for (int j4 = 0; j4 < NPER/4; j4++){
            float4 v = sc4[j4];
            int j = j4*4;
            rank += (v.x > s) || (v.x == s && (j+0) < t);   // stable tie-break = lax.top_k
            rank += (v.y > s) || (v.y == s && (j+1) < t);
            rank += (v.z > s) || (v.z == s && (j+2) < t);
            rank += (v.w > s) || (v.w == s && (j+3) < t);
        }
        if (rank < K){
            nid[t] = g*K + rank;
            selg[g*K + rank] = gbase + t;       // source row in the conv-output buffer
            thg[g*K + rank]  = tanhf(s);
        } else nid[t] = -1;
    }
    __syncthreads();
    if (BUILD){
        for (int i = t; i < EPG; i += 512){
            int e = g*EPG + i;
            int d = edst_in[e];
            if (d < 0) continue;
            int s_ = esrc_in[e];
            int ns = nid[s_ - gbase], nd = nid[d - gbase];
            if ((ns | nd) < 0){ edst_out[e] = -1; }
            else {
                esrc_out[e] = ns; edst_out[e] = nd;
                int ndl = nd & (K-1);
                int slot = atomicAdd(&lcnt[ndl], 1);
                if (slot < DEGMAX) csrS[ndl*DEGMAX + slot] = (unsigned short)(ns & (K-1));
            }
        }
        __syncthreads();               // csrS + lcnt ready
        {   // coalesced CSR writeout for next stage's k_prop
            unsigned* c32 = (unsigned*)csrS;
            unsigned* dst = (unsigned*)(csrcp + (size_t)g*K*DEGMAX);
            for (int i = t; i < K*DEGMAX/2; i += 512) dst[i] = c32[i];
        }
        float* yd = sc;                // reuse: sc dead after rank; 2*K == NPER floats
        int rawc = 0, dc = 0;
        if (t < K){
            rawc = lcnt[t];
            cnt_next[g*K + t] = rawc;
            dc = min(rawc, DEGMAX);
            atomicAdd(&bins[dc], 1);
        }
        __syncthreads();
        if (t < 64){
            int v0 = bins[t], s = v0;
            #pragma unroll
            for (int off = 1; off < 64; off <<= 1){
                int n = __shfl_up(s, off);
                if (t >= off) s += n;
            }
            bins[t] = s - v0;
        }
        __syncthreads();
        if (t < K){
            int slot = atomicAdd(&bins[dc], 1);
            permS[slot] = t | (dc << 16);
            permg[g*K + slot] = permS[slot];
        }
        __syncthreads();
        int pv = 0, pd = 0;
        if (t < K){
            int pk = permS[t];
            pv = pk & 0xffff; pd = pk >> 16;
            yd[pv] = 1.f;
        }
        __syncthreads();
        float dacc = 1.f;
        int cur = 0;
        for (int l = 0; l < 2; l++){
            if (t < K){
                const float* la = &yd[cur*K];
                float s = 0.f;
                int nq = (pd + 3) >> 2;
                const u16x4* cp = (const u16x4*)(csrS + pv*DEGMAX);   // LDS
                u16x4 oc = cp[0];
                #pragma unroll 1
                for (int jq = 0; jq < nq; jq++){
                    u16x4 ocn = cp[jq + 1];
                    s += (la[(int)oc[0]] + la[(int)oc[1]]) + (la[(int)oc[2]] + la[(int)oc[3]]);
                    oc = ocn;
                }
                if (nq) s -= (float)(nq*4 - pd) * la[0];
                yd[(1^cur)*K + pv] = s;
                dacc += s;
            }
            __syncthreads();
            cur ^= 1;
        }
        if (t < K) dinvg[g*K + pv] = rsqrtf(fmaxf(dacc, 1e-12f));
    }
}

// ---------------- fused stage 3: per-graph conv3 GEMM + score + rank + mean + MLP ----------------
__global__ __launch_bounds__(512) void k_stage3(const float* __restrict__ X,
        const float* __restrict__ W, const float* __restrict__ bias,
        const float* __restrict__ p, const float* __restrict__ beta,
        const int* __restrict__ cntv,
        const float* __restrict__ W1, const float* __restrict__ b1,
        const float* __restrict__ W2, const float* __restrict__ b2,
        float* __restrict__ out){
    __shared__ __align__(16) char smem[70912];
    __shared__ float scs[128];
    __shared__ float thS[64];
    __shared__ int   selS[64];
    __shared__ float mr[128];
    short* wsh = (short*)smem;
    short* wsl = (short*)(smem + 34816);
    float* bsh = (float*)(smem + 69632);
    float* qs  = (float*)(smem + 70144);
    float* rednorm = (float*)(smem + 70656);
    int g = blockIdx.x, t = threadIdx.x;
    for (int e = t; e < 16384; e += 512){
        int k = e >> 7, n = e & 127;
        short hi, lo; split_bf16(W[e], hi, lo);
        wsh[n*136 + k] = hi; wsl[n*136 + k] = lo;
    }
    if (t < 128) bsh[t] = bias[t];
    if (t < 64){ float a = p[t], b = p[t+64]; rednorm[t] = a*a + b*b; }
    __syncthreads();
    if (t == 0){ float s = 0.f; for (int i = 0; i < 64; i++) s += rednorm[i]; rednorm[0] = sqrtf(s); }
    __syncthreads();
    if (t < 128) qs[t] = beta[0] * p[t] / rednorm[0];
    float b1v = beta[1];
    __syncthreads();
    int wave = t >> 6, lane = t & 63;
    int ln = lane & 15, q = lane >> 4;
    const float* xrow = &X[((size_t)g*128 + wave*16 + ln)*128 + q*8];
    f32x4 acc[8];
    #pragma unroll
    for (int i = 0; i < 8; i++) acc[i] = (f32x4){0.f,0.f,0.f,0.f};
    #pragma unroll
    for (int kc = 0; kc < 4; kc++){
        float4 xa = *(const float4*)(xrow + kc*32);
        float4 xb = *(const float4*)(xrow + kc*32 + 4);
        bf16x8 ah, al; short hi, lo;
        split_bf16(xa.x, hi, lo); ah[0]=hi; al[0]=lo;
        split_bf16(xa.y, hi, lo); ah[1]=hi; al[1]=lo;
        split_bf16(xa.z, hi, lo); ah[2]=hi; al[2]=lo;
        split_bf16(xa.w, hi, lo); ah[3]=hi; al[3]=lo;
        split_bf16(xb.x, hi, lo); ah[4]=hi; al[4]=lo;
        split_bf16(xb.y, hi, lo); ah[5]=hi; al[5]=lo;
        split_bf16(xb.z, hi, lo); ah[6]=hi; al[6]=lo;
        split_bf16(xb.w, hi, lo); ah[7]=hi; al[7]=lo;
        #pragma unroll
        for (int nt = 0; nt < 8; nt++){
            int wo = (nt*16 + ln)*136 + kc*32 + q*8;
            bf16x8 bh = *(const bf16x8*)&wsh[wo];
            bf16x8 bl = *(const bf16x8*)&wsl[wo];
            acc[nt] = __builtin_amdgcn_mfma_f32_16x16x32_bf16(ah, bh, acc[nt], 0, 0, 0);
            acc[nt] = __builtin_amdgcn_mfma_f32_16x16x32_bf16(ah, bl, acc[nt], 0, 0, 0);
            acc[nt] = __builtin_amdgcn_mfma_f32_16x16x32_bf16(al, bh, acc[nt], 0, 0, 0);
        }
    }
    // score from regs
    #pragma unroll
    for (int r = 0; r < 4; r++){
        float sp = 0.f;
        #pragma unroll
        for (int nt = 0; nt < 8; nt++){
            int c = nt*16 + ln;
            sp += (acc[nt][r] + bsh[c]) * qs[c];
        }
        sp += __shfl_xor(sp, 1);
        sp += __shfl_xor(sp, 2);
        sp += __shfl_xor(sp, 4);
        sp += __shfl_xor(sp, 8);
        if (ln == 0){
            int rl = wave*16 + q*4 + r;
            scs[rl] = sp + b1v * (float)cntv[g*128 + rl];
        }
    }
    __syncthreads();                       // wsh/wsl reads done -> safe to overwrite
    float* Yl = (float*)smem;              // [128][132]
    #pragma unroll
    for (int nt = 0; nt < 8; nt++){
        int c = nt*16 + ln;
        float bb = bsh[c];
        #pragma unroll
        for (int r = 0; r < 4; r++){
            Yl[(wave*16 + q*4 + r)*132 + c] = acc[nt][r] + bb;
        }
    }
    __syncthreads();
    if (t < 128){
        float s = scs[t];
        int rank = 0;
        const float4* sc4 = (const float4*)scs;
        #pragma unroll 8
        for (int j4 = 0; j4 < 32; j4++){
            float4 v = sc4[j4];
            int j = j4*4;
            rank += (v.x > s) || (v.x == s && (j+0) < t);   // stable tie-break = lax.top_k
            rank += (v.y > s) || (v.y == s && (j+1) < t);
            rank += (v.z > s) || (v.z == s && (j+2) < t);
            rank += (v.w > s) || (v.w == s && (j+3) < t);
        }
        if (rank < 64){ selS[rank] = t; thS[rank] = tanhf(s); }
    }
    __syncthreads();
    if (t < 128){
        float s = 0.f;
        #pragma unroll 8
        for (int r = 0; r < 64; r++) s += Yl[selS[r]*132 + t] * thS[r];
        mr[t] = s * (1.f/64.f);
    }
    __syncthreads();
    if (t < 64){
        float a = b1[t];
        #pragma unroll 8
        for (int k = 0; k < 128; k++) a += mr[k]*W1[k*64 + t];
        a = fmaxf(a, 0.f);
        float r = a * W2[t];
        #pragma unroll
        for (int off = 32; off > 0; off >>= 1) r += __shfl_down(r, off);
        if (t == 0) out[g] = r + b2[0];
    }
}

// ---------------- driver: 10 launches ----------------
extern "C" void kernel_launch(void* const* d_in, const int* in_sizes, int n_in,
                              void* d_out, int out_size, void* d_ws, size_t ws_size,
                              hipStream_t stream){
    (void)in_sizes; (void)n_in; (void)out_size; (void)ws_size;
    const float* x     = (const float*)d_in[0];
    const int*   ei    = (const int*)d_in[1];
    const float* lumpW = (const float*)d_in[3];
    const float* lumpb = (const float*)d_in[4];
    const float* convW[3]    = {(const float*)d_in[5], (const float*)d_in[7], (const float*)d_in[9]};
    const float* convB[3]    = {(const float*)d_in[6], (const float*)d_in[8], (const float*)d_in[10]};
    const float* poolP[3]    = {(const float*)d_in[11], (const float*)d_in[13], (const float*)d_in[15]};
    const float* poolBeta[3] = {(const float*)d_in[12], (const float*)d_in[14], (const float*)d_in[16]};
    const float* lin1W = (const float*)d_in[17];
    const float* lin1b = (const float*)d_in[18];
    const float* lin2W = (const float*)d_in[19];
    const float* lin2b = (const float*)d_in[20];
    float* out = (float*)d_out;

    char* w8 = (char*)d_ws;
    size_t off = 0;
    auto alloc = [&](size_t bytes)->char*{
        char* p = w8 + off; off += (bytes + 255) & ~(size_t)255; return p;
    };
    float* A     = (float*)alloc((size_t)65536*128*4);
    float* Bb    = (float*)alloc((size_t)65536*128*4);
    int*   srcA  = (int*)alloc((size_t)E_*4);
    int*   dstA  = (int*)alloc((size_t)E_*4);
    unsigned short* csr1 = (unsigned short*)alloc((size_t)65536*DEGMAX*2);
    unsigned short* csr2 = (unsigned short*)alloc((size_t)32768*DEGMAX*2);
    unsigned short* csr3 = (unsigned short*)alloc((size_t)16384*DEGMAX*2);
    int*   cntA  = (int*)alloc((size_t)(65536+32768+16384)*4);
    int*   cnt1 = cntA, *cnt2 = cntA + 65536, *cnt3 = cntA + 98304;
    int*   perm1 = (int*)alloc((size_t)65536*4);
    int*   perm2 = (int*)alloc((size_t)32768*4);
    int*   perm3 = (int*)alloc((size_t)16384*4);
    float* dinv1 = (float*)alloc((size_t)65536*4);
    float* dinv2 = (float*)alloc((size_t)32768*4);
    float* dinv3 = (float*)alloc((size_t)16384*4);
    float* score1 = (float*)alloc((size_t)65536*4);
    float* score2 = (float*)alloc((size_t)32768*4);
    int*   sel2  = (int*)alloc((size_t)32768*4);
    int*   sel3  = (int*)alloc((size_t)16384*4);
    float* th2   = (float*)alloc((size_t)32768*4);
    float* th3   = (float*)alloc((size_t)16384*4);

    // ----- prep1 (LDS CSR build) then lump GEMM -----
    k_prep1<<<G_, 512, 0, stream>>>(ei, cnt1, csr1, perm1, dinv1);
    k_gemm_mfma<8><<<512, 512, 0, stream>>>(x, lumpW, lumpb, A,
            nullptr, nullptr, nullptr, nullptr);

    // ----- stage 1: conv1 (L=4, nper=512), pool -> 256/graph -----
    k_prop<512,4,4,false><<<dim3(G_,4), 1024, 0, stream>>>(perm1, dinv1, csr1, A,
            nullptr, nullptr, Bb);
    k_gemm_mfma<8><<<512, 512, 0, stream>>>(Bb, convW[0], convB[0], A,
            poolP[0], poolBeta[0], cnt1, score1);
    k_pooltop<512,true><<<G_, 512, 0, stream>>>(score1, ei, ei + E_, srcA, dstA,
            cnt2, csr2, perm2, dinv2, sel2, th2);

    // ----- stage 2: conv2 (L=2, nper=256), pool -> 128/graph -----
    k_prop<256,2,2,true><<<dim3(G_,4), 1024, 0, stream>>>(perm2, dinv2, csr2, A,
            sel2, th2, Bb);
    k_gemm_mfma<8><<<256, 512, 0, stream>>>(Bb, convW[1], convB[1], A,
            poolP[1], poolBeta[1], cnt2, score2);
    k_pooltop<256,true><<<G_, 512, 0, stream>>>(score2, srcA, dstA, srcA, dstA,
            cnt3, csr3, perm3, dinv3, sel3, th3);

    // ----- stage 3: conv3 (L=2, nper=128) then fused conv3-gemm+pool+mean+MLP -----
    k_prop<128,2,1,true><<<dim3(G_,4), 1024, 0, stream>>>(perm3, dinv3, csr3, A,
            sel3, th3, Bb);
    k_stage3<<<G_, 512, 0, stream>>>(Bb, convW[2], convB[2],
            poolP[2], poolBeta[2], cnt3, lin1W, lin1b, lin2W, lin2b, out);
}

// Round 11
// 273.861 us; speedup vs baseline: 1.0374x; 1.0374x over previous
//
#include <hip/hip_runtime.h>
#include <math.h>

#define G_     128
#define E_     524288
#define EPG    4096
#define DEGMAX 48

typedef __attribute__((ext_vector_type(8))) short bf16x8;
typedef __attribute__((ext_vector_type(4))) float f32x4;
typedef __attribute__((ext_vector_type(4))) unsigned short u16x4;

__device__ inline void split_bf16(float x, short& hi, short& lo){
    unsigned u = __float_as_uint(x);
    hi = (short)(u >> 16);
    float hf = __uint_as_float(u & 0xffff0000u);
    unsigned r = __float_as_uint(x - hf);
    lo = (short)(r >> 16);
}

// ================= W pre-split: W(f32 128x128) -> hi/lo shorts in padded [n*136+k] =================
// Done ONCE per matrix; removes 16384 loads + 16384 split_bf16 + 32768 scattered LDS
// stores from EVERY GEMM block (1408 block-stagings total). Stores coalesced
// (consecutive e -> consecutive k -> adjacent u16). Pads [128,136) never read.
__global__ __launch_bounds__(256) void k_splitW(const float* __restrict__ W0,
        const float* __restrict__ W1, const float* __restrict__ W2,
        const float* __restrict__ W3, unsigned short* __restrict__ outw){
    int mat = blockIdx.x >> 3, blk = blockIdx.x & 7;
    const float* W = (mat==0)?W0:(mat==1)?W1:(mat==2)?W2:W3;
    unsigned short* hi = outw + (size_t)mat*2*17408;
    unsigned short* lo = hi + 17408;
    for (int e = blk*256 + threadIdx.x; e < 16384; e += 2048){
        int k = e >> 7, n = e & 127;
        short h, l; split_bf16(W[e], h, l);
        hi[n*136 + k] = h; lo[n*136 + k] = l;
    }
}

// ================= shared GEMM body: Y = X(Mx128) @ W(128x128) + bias (+score) =================
// Wsp = pre-split hi/lo shorts (padded layout) -> prologue is a pure coalesced copy.
// smem layout: wsh[0,34816) wsl[34816,69632) bsh[69632,70144) qs[70144,70656) red[70656,70912)
template<int WAVES>
__device__ void gemm_body(char* smem, int bid, const float* __restrict__ X,
        const unsigned short* __restrict__ Wsp, const float* __restrict__ bias,
        float* __restrict__ Y,
        const float* __restrict__ p, const float* __restrict__ beta,
        const int* __restrict__ cntv, float* __restrict__ score){
    short* wsh = (short*)smem;
    short* wsl = (short*)(smem + 34816);
    float* bsh = (float*)(smem + 69632);
    float* qs  = (float*)(smem + 70144);
    float* rednorm = (float*)(smem + 70656);
    const int NT = WAVES*64;
    int t = threadIdx.x;
    {
        const unsigned* h32 = (const unsigned*)Wsp;             // 8704 u32
        const unsigned* l32 = (const unsigned*)(Wsp + 17408);
        unsigned* wsh32 = (unsigned*)wsh;
        unsigned* wsl32 = (unsigned*)wsl;
        for (int i = t; i < 8704; i += NT){ wsh32[i] = h32[i]; wsl32[i] = l32[i]; }
    }
    if (t < 128) bsh[t] = bias[t];
    if (score && t < 64){ float a = p[t], b = p[t+64]; rednorm[t] = a*a + b*b; }
    __syncthreads();
    float b1 = 0.f;
    if (score){
        if (t == 0){ float s = 0.f; for (int i = 0; i < 64; i++) s += rednorm[i]; rednorm[0] = sqrtf(s); }
        __syncthreads();
        if (t < 128) qs[t] = beta[0] * p[t] / rednorm[0];
        b1 = beta[1];
        __syncthreads();
    }
    int wave = t >> 6, lane = t & 63;
    int ln = lane & 15, q = lane >> 4;
    size_t rb = (size_t)bid * (WAVES*16);
    const float* xrow = &X[(rb + wave*16 + ln)*128 + q*8];
    f32x4 acc[8];
    #pragma unroll
    for (int i = 0; i < 8; i++) acc[i] = (f32x4){0.f,0.f,0.f,0.f};
    #pragma unroll
    for (int kc = 0; kc < 4; kc++){
        float4 xa = *(const float4*)(xrow + kc*32);
        float4 xb = *(const float4*)(xrow + kc*32 + 4);
        bf16x8 ah, al; short hi, lo;
        split_bf16(xa.x, hi, lo); ah[0]=hi; al[0]=lo;
        split_bf16(xa.y, hi, lo); ah[1]=hi; al[1]=lo;
        split_bf16(xa.z, hi, lo); ah[2]=hi; al[2]=lo;
        split_bf16(xa.w, hi, lo); ah[3]=hi; al[3]=lo;
        split_bf16(xb.x, hi, lo); ah[4]=hi; al[4]=lo;
        split_bf16(xb.y, hi, lo); ah[5]=hi; al[5]=lo;
        split_bf16(xb.z, hi, lo); ah[6]=hi; al[6]=lo;
        split_bf16(xb.w, hi, lo); ah[7]=hi; al[7]=lo;
        #pragma unroll
        for (int nt = 0; nt < 8; nt++){
            int wo = (nt*16 + ln)*136 + kc*32 + q*8;
            bf16x8 bh = *(const bf16x8*)&wsh[wo];
            bf16x8 bl = *(const bf16x8*)&wsl[wo];
            acc[nt] = __builtin_amdgcn_mfma_f32_16x16x32_bf16(ah, bh, acc[nt], 0, 0, 0);
            acc[nt] = __builtin_amdgcn_mfma_f32_16x16x32_bf16(ah, bl, acc[nt], 0, 0, 0);
            acc[nt] = __builtin_amdgcn_mfma_f32_16x16x32_bf16(al, bh, acc[nt], 0, 0, 0);
        }
    }
    #pragma unroll
    for (int nt = 0; nt < 8; nt++){
        int c = nt*16 + ln;
        float bb = bsh[c];
        #pragma unroll
        for (int r = 0; r < 4; r++){
            Y[(rb + wave*16 + q*4 + r)*128 + c] = acc[nt][r] + bb;
        }
    }
    if (score){
        #pragma unroll
        for (int r = 0; r < 4; r++){
            float sp = 0.f;
            #pragma unroll
            for (int nt = 0; nt < 8; nt++){
                int c = nt*16 + ln;
                sp += (acc[nt][r] + bsh[c]) * qs[c];
            }
            sp += __shfl_xor(sp, 1);
            sp += __shfl_xor(sp, 2);
            sp += __shfl_xor(sp, 4);
            sp += __shfl_xor(sp, 8);
            if (ln == 0){
                int row = (int)rb + wave*16 + q*4 + r;
                score[row] = sp + b1 * (float)cntv[row];
            }
        }
    }
}

// ================= standalone GEMM (+score) =================
template<int WAVES>
__global__ __launch_bounds__(WAVES*64) void k_gemm_mfma(const float* __restrict__ X,
        const unsigned short* __restrict__ Wsp, const float* __restrict__ bias,
        float* __restrict__ Y,
        const float* __restrict__ p, const float* __restrict__ beta,
        const int* __restrict__ cntv, float* __restrict__ score){
    __shared__ __align__(16) char smem[70912];
    gemm_body<WAVES>(smem, blockIdx.x, X, Wsp, bias, Y, p, beta, cntv, score);
}

// ================= stage-1 prep: LDS-built CSR + coalesced writeout + sort + degree-prop =================
// R21 (proven): CSR built in LDS, written to global coalesced, degree-prop reads LDS.
__global__ __launch_bounds__(512) void k_prep1(const int* __restrict__ ei,
        int* __restrict__ cnt, unsigned short* __restrict__ csrcp,
        int* __restrict__ permg, float* __restrict__ dinvg){
    __shared__ int   lcnt[512];
    __shared__ __align__(16) unsigned short csrS[512*DEGMAX + 8];  // 49168 B (+8B prefetch pad)
    __shared__ float y[1024];          // degree ping-pong
    __shared__ int   bins[64];
    __shared__ int   permS[512];
    int g = blockIdx.x, t = threadIdx.x, gbase = g*512;
    lcnt[t] = 0;
    if (t < 64) bins[t] = 0;
    unsigned* c32 = (unsigned*)csrS;
    for (int i = t; i < 512*DEGMAX/2 + 4; i += 512) c32[i] = 0;
    __syncthreads();
    for (int i = t; i < EPG; i += 512){
        int e = g*EPG + i;
        int sv = ei[e] & 511;          // ids are g*512+local; 512-aligned -> &511 = local
        int d  = ei[E_ + e] & 511;
        int slot = atomicAdd(&lcnt[d], 1);
        if (slot < DEGMAX) csrS[d*DEGMAX + slot] = (unsigned short)sv;
    }
    __syncthreads();                   // csrS + lcnt ready
    {   // coalesced CSR writeout (k_prop reads it from global)
        unsigned* dst = (unsigned*)(csrcp + (size_t)gbase*DEGMAX);
        for (int i = t; i < 512*DEGMAX/2; i += 512) dst[i] = c32[i];
    }
    int rawc = lcnt[t];
    cnt[gbase + t] = rawc;             // GEMM score epilogue's node-strength term (unclamped)
    int dc = min(rawc, DEGMAX);
    atomicAdd(&bins[dc], 1);
    __syncthreads();
    if (t < 64){
        int v0 = bins[t], s = v0;
        #pragma unroll
        for (int off = 1; off < 64; off <<= 1){
            int n = __shfl_up(s, off);
            if (t >= off) s += n;
        }
        bins[t] = s - v0;              // exclusive prefix
    }
    __syncthreads();
    {
        int slot = atomicAdd(&bins[dc], 1);
        int pk = t | (dc << 16);
        permS[slot] = pk;
        permg[gbase + slot] = pk;
    }
    __syncthreads();
    int pk = permS[t];
    int pv = pk & 0xffff, pd = pk >> 16;
    y[pv] = 1.f;
    __syncthreads();
    float dacc = 1.f;
    int cur = 0;
    for (int l = 0; l < 4; l++){
        const float* la = &y[cur*512];
        float s = 0.f;
        int nq = (pd + 3) >> 2;
        const u16x4* cp = (const u16x4*)(csrS + pv*DEGMAX);   // LDS
        u16x4 oc = cp[0];
        #pragma unroll 1
        for (int jq = 0; jq < nq; jq++){
            u16x4 ocn = cp[jq + 1];    // +8B over-read lands in csrS pad
            s += (la[(int)oc[0]] + la[(int)oc[1]]) + (la[(int)oc[2]] + la[(int)oc[3]]);
            oc = ocn;
        }
        if (nq) s -= (float)(nq*4 - pd) * la[0];
        y[(1^cur)*512 + pv] = s;
        dacc += s;
        __syncthreads();
        cur ^= 1;
    }
    dinvg[gbase + pv] = rsqrtf(fmaxf(dacc, 1e-12f));
}

// ---------------- per-graph feature prop (R19/R21 exact form — ysw REVERTED) ----------------
// OUT = dinv * (sum_l A^l)(dinv * x). R15 tiling (1024 thr, fq=4, 128B row stride).
// BANK-CONFLICT HISTORY (DO NOT RE-SWIZZLE): the unswizzled gather is STRUCTURED-
// OPTIMAL — each wave reads 8 full 128B rows; every row covers all 32 banks once, so
// each bank serves exactly 8 accesses = the wave64-b128 floor. R22's XOR swizzle
// randomized this balance: conflicts 3.15M -> 4.72M, dur 43.0 -> 49.4. R16's 64B
// stride also doubled conflicts. 128B contiguous rows, no swizzle, is the optimum.
// R20's CSR-LDS staging was neutral-negative (TLP already hides CSR latency).
// REGISTER HISTORY (DO NOT REPEAT): min-waves hints (R7/R14 launch_bounds(1024,8))
// force a 32-VGPR ceiling -> catastrophic scratch spill (FETCH 20->160MB).
template<int NPER, int L, int IT, bool SEL>
__global__ __launch_bounds__(1024)
void k_prop(const int* __restrict__ permg, const float* __restrict__ dinvg,
        const unsigned short* __restrict__ csrcp,
        const float* __restrict__ X, const int* __restrict__ selg,
        const float* __restrict__ thg, float* __restrict__ OUT){
    __shared__ __align__(16) float y[NPER*32];
    __shared__ float dinvs[NPER];
    int g = blockIdx.x, fq = blockIdx.y, gbase = g*NPER;
    int t = threadIdx.x;
    int f4 = (t & 7)*4;
    int fo = fq*32 + f4;
    if (t < NPER) dinvs[t] = dinvg[gbase + t];
    int pkr[IT];
    {
        int wv = t >> 6, gi = (t >> 3) & 7;
        #pragma unroll
        for (int it = 0; it < IT; it++){
            int ch = (it & 1) ? (15 - wv) : wv;
            pkr[it] = permg[gbase + (16*it + ch)*8 + gi];
        }
    }
    __syncthreads();
    float4 acc[IT];
    #pragma unroll
    for (int it = 0; it < IT; it++){
        int v = pkr[it] & 0xffff;
        float d = dinvs[v];
        size_t row;
        if (SEL){
            row = (size_t)selg[gbase + v];
            d *= thg[gbase + v];
        } else {
            row = (size_t)(gbase + v);
        }
        float4 w = *(const float4*)&X[row*128 + fo];
        w.x*=d; w.y*=d; w.z*=d; w.w*=d;
        acc[it] = w;
        *(float4*)&y[v*32 + f4] = w;
    }
    __syncthreads();
    for (int l = 0; l < L; l++){
        float4 s[IT];
        #pragma unroll
        for (int it = 0; it < IT; it++){
            int pk = pkr[it];
            int c = pk >> 16;
            int nq = (c + 3) >> 2;
            const u16x4* cp = (const u16x4*)(csrcp + (size_t)(gbase + (pk & 0xffff))*DEGMAX);
            float4 ss = make_float4(0.f,0.f,0.f,0.f);
            u16x4 oc = cp[0];
            #pragma unroll 1
            for (int jq = 0; jq < nq; jq++){
                u16x4 ocn = cp[jq + 1];
                float4 w0 = *(const float4*)&y[((int)oc[0])*32 + f4];
                float4 w1 = *(const float4*)&y[((int)oc[1])*32 + f4];
                float4 w2 = *(const float4*)&y[((int)oc[2])*32 + f4];
                float4 w3 = *(const float4*)&y[((int)oc[3])*32 + f4];
                ss.x += (w0.x + w1.x) + (w2.x + w3.x);
                ss.y += (w0.y + w1.y) + (w2.y + w3.y);
                ss.z += (w0.z + w1.z) + (w2.z + w3.z);
                ss.w += (w0.w + w1.w) + (w2.w + w3.w);
                oc = ocn;
            }
            if (nq){
                float fp = (float)(nq*4 - c);
                float4 z = *(const float4*)&y[f4];          // row 0 (broadcast)
                ss.x -= fp*z.x; ss.y -= fp*z.y; ss.z -= fp*z.z; ss.w -= fp*z.w;
            }
            s[it] = ss;
        }
        __syncthreads();
        #pragma unroll
        for (int it = 0; it < IT; it++){
            int v = pkr[it] & 0xffff;
            *(float4*)&y[v*32 + f4] = s[it];
            acc[it].x+=s[it].x; acc[it].y+=s[it].y; acc[it].z+=s[it].z; acc[it].w+=s[it].w;
        }
        __syncthreads();
    }
    #pragma unroll
    for (int it = 0; it < IT; it++){
        int v = pkr[it] & 0xffff;
        float d = dinvs[v];
        float4 w = acc[it];
        w.x*=d; w.y*=d; w.z*=d; w.w*=d;
        *(float4*)&OUT[(size_t)(gbase + v)*128 + fo] = w;
    }
}

// ---------------- pooling control: rank + sel/th emit + edge remap + next-stage prep ----------------
// R22/R23: next-stage CSR built in LDS (proven R21 pattern), coalesced u32 writeout,
// tail degree-prop reads LDS. Pads stay 0 from the LDS memset.
template<int NPER, bool BUILD>
__global__ __launch_bounds__(512) void k_pooltop(const float* __restrict__ score_in,
        const int* __restrict__ esrc_in, const int* __restrict__ edst_in,
        int* __restrict__ esrc_out, int* __restrict__ edst_out,
        int* __restrict__ cnt_next, unsigned short* __restrict__ csrcp,
        int* __restrict__ permg, float* __restrict__ dinvg,
        int* __restrict__ selg, float* __restrict__ thg){
    const int K = NPER/2;
    constexpr int CSRSZ = BUILD ? (NPER/2)*DEGMAX + 8 : 8;
    __shared__ __align__(16) float sc[NPER];
    __shared__ int  nid[NPER];
    __shared__ int  lcnt[NPER/2];
    __shared__ int  bins[64];
    __shared__ int  permS[NPER/2];
    __shared__ __align__(16) unsigned short csrS[CSRSZ];
    int g = blockIdx.x, t = threadIdx.x, gbase = g*NPER;
    if (t < K) lcnt[t] = 0;
    if (t < 64) bins[t] = 0;
    if (BUILD){
        unsigned* c32 = (unsigned*)csrS;
        for (int i = t; i < K*DEGMAX/2 + 4; i += 512) c32[i] = 0;
    }
    if (t < NPER) sc[t] = score_in[gbase + t];
    __syncthreads();
    if (t < NPER){
        float s = sc[t];
        int rank = 0;
        const float4* sc4 = (const float4*)sc;
        #pragma unroll 8
        for (int j4 = 0; j4 < NPER/4; j4++){
            float4 v = sc4[j4];
            int j = j4*4;
            rank += (v.x > s) || (v.x == s && (j+0) < t);   // stable tie-break = lax.top_k
            rank += (v.y > s) || (v.y == s && (j+1) < t);
            rank += (v.z > s) || (v.z == s && (j+2) < t);
            rank += (v.w > s) || (v.w == s && (j+3) < t);
        }
        if (rank < K){
            nid[t] = g*K + rank;
            selg[g*K + rank] = gbase + t;       // source row in the conv-output buffer
            thg[g*K + rank]  = tanhf(s);
        } else nid[t] = -1;
    }
    __syncthreads();
    if (BUILD){
        for (int i = t; i < EPG; i += 512){
            int e = g*EPG + i;
            int d = edst_in[e];
            if (d < 0) continue;
            int s_ = esrc_in[e];
            int ns = nid[s_ - gbase], nd = nid[d - gbase];
            if ((ns | nd) < 0){ edst_out[e] = -1; }
            else {
                esrc_out[e] = ns; edst_out[e] = nd;
                int ndl = nd & (K-1);
                int slot = atomicAdd(&lcnt[ndl], 1);
                if (slot < DEGMAX) csrS[ndl*DEGMAX + slot] = (unsigned short)(ns & (K-1));
            }
        }
        __syncthreads();               // csrS + lcnt ready
        {   // coalesced CSR writeout for next stage's k_prop
            unsigned* c32 = (unsigned*)csrS;
            unsigned* dst = (unsigned*)(csrcp + (size_t)g*K*DEGMAX);
            for (int i = t; i < K*DEGMAX/2; i += 512) dst[i] = c32[i];
        }
        float* yd = sc;                // reuse: sc dead after rank; 2*K == NPER floats
        int rawc = 0, dc = 0;
        if (t < K){
            rawc = lcnt[t];
            cnt_next[g*K + t] = rawc;
            dc = min(rawc, DEGMAX);
            atomicAdd(&bins[dc], 1);
        }
        __syncthreads();
        if (t < 64){
            int v0 = bins[t], s = v0;
            #pragma unroll
            for (int off = 1; off < 64; off <<= 1){
                int n = __shfl_up(s, off);
                if (t >= off) s += n;
            }
            bins[t] = s - v0;
        }
        __syncthreads();
        if (t < K){
            int slot = atomicAdd(&bins[dc], 1);
            permS[slot] = t | (dc << 16);
            permg[g*K + slot] = permS[slot];
        }
        __syncthreads();
        int pv = 0, pd = 0;
        if (t < K){
            int pk = permS[t];
            pv = pk & 0xffff; pd = pk >> 16;
            yd[pv] = 1.f;
        }
        __syncthreads();
        float dacc = 1.f;
        int cur = 0;
        for (int l = 0; l < 2; l++){
            if (t < K){
                const float* la = &yd[cur*K];
                float s = 0.f;
                int nq = (pd + 3) >> 2;
                const u16x4* cp = (const u16x4*)(csrS + pv*DEGMAX);   // LDS
                u16x4 oc = cp[0];
                #pragma unroll 1
                for (int jq = 0; jq < nq; jq++){
                    u16x4 ocn = cp[jq + 1];
                    s += (la[(int)oc[0]] + la[(int)oc[1]]) + (la[(int)oc[2]] + la[(int)oc[3]]);
                    oc = ocn;
                }
                if (nq) s -= (float)(nq*4 - pd) * la[0];
                yd[(1^cur)*K + pv] = s;
                dacc += s;
            }
            __syncthreads();
            cur ^= 1;
        }
        if (t < K) dinvg[g*K + pv] = rsqrtf(fmaxf(dacc, 1e-12f));
    }
}

// ---------------- fused stage 3: per-graph conv3 GEMM + score + rank + mean + MLP ----------------
__global__ __launch_bounds__(512) void k_stage3(const float* __restrict__ X,
        const unsigned short* __restrict__ Wsp, const float* __restrict__ bias,
        const float* __restrict__ p, const float* __restrict__ beta,
        const int* __restrict__ cntv,
        const float* __restrict__ W1, const float* __restrict__ b1,
        const float* __restrict__ W2, const float* __restrict__ b2,
        float* __restrict__ out){
    __shared__ __align__(16) char smem[70912];
    __shared__ float scs[128];
    __shared__ float thS[64];
    __shared__ int   selS[64];
    __shared__ float mr[128];
    short* wsh = (short*)smem;
    short* wsl = (short*)(smem + 34816);
    float* bsh = (float*)(smem + 69632);
    float* qs  = (float*)(smem + 70144);
    float* rednorm = (float*)(smem + 70656);
    int g = blockIdx.x, t = threadIdx.x;
    {
        const unsigned* h32 = (const unsigned*)Wsp;
        const unsigned* l32 = (const unsigned*)(Wsp + 17408);
        unsigned* wsh32 = (unsigned*)wsh;
        unsigned* wsl32 = (unsigned*)wsl;
        for (int i = t; i < 8704; i += 512){ wsh32[i] = h32[i]; wsl32[i] = l32[i]; }
    }
    if (t < 128) bsh[t] = bias[t];
    if (t < 64){ float a = p[t], b = p[t+64]; rednorm[t] = a*a + b*b; }
    __syncthreads();
    if (t == 0){ float s = 0.f; for (int i = 0; i < 64; i++) s += rednorm[i]; rednorm[0] = sqrtf(s); }
    __syncthreads();
    if (t < 128) qs[t] = beta[0] * p[t] / rednorm[0];
    float b1v = beta[1];
    __syncthreads();
    int wave = t >> 6, lane = t & 63;
    int ln = lane & 15, q = lane >> 4;
    const float* xrow = &X[((size_t)g*128 + wave*16 + ln)*128 + q*8];
    f32x4 acc[8];
    #pragma unroll
    for (int i = 0; i < 8; i++) acc[i] = (f32x4){0.f,0.f,0.f,0.f};
    #pragma unroll
    for (int kc = 0; kc < 4; kc++){
        float4 xa = *(const float4*)(xrow + kc*32);
        float4 xb = *(const float4*)(xrow + kc*32 + 4);
        bf16x8 ah, al; short hi, lo;
        split_bf16(xa.x, hi, lo); ah[0]=hi; al[0]=lo;
        split_bf16(xa.y, hi, lo); ah[1]=hi; al[1]=lo;
        split_bf16(xa.z, hi, lo); ah[2]=hi; al[2]=lo;
        split_bf16(xa.w, hi, lo); ah[3]=hi; al[3]=lo;
        split_bf16(xb.x, hi, lo); ah[4]=hi; al[4]=lo;
        split_bf16(xb.y, hi, lo); ah[5]=hi; al[5]=lo;
        split_bf16(xb.z, hi, lo); ah[6]=hi; al[6]=lo;
        split_bf16(xb.w, hi, lo); ah[7]=hi; al[7]=lo;
        #pragma unroll
        for (int nt = 0; nt < 8; nt++){
            int wo = (nt*16 + ln)*136 + kc*32 + q*8;
            bf16x8 bh = *(const bf16x8*)&wsh[wo];
            bf16x8 bl = *(const bf16x8*)&wsl[wo];
            acc[nt] = __builtin_amdgcn_mfma_f32_16x16x32_bf16(ah, bh, acc[nt], 0, 0, 0);
            acc[nt] = __builtin_amdgcn_mfma_f32_16x16x32_bf16(ah, bl, acc[nt], 0, 0, 0);
            acc[nt] = __builtin_amdgcn_mfma_f32_16x16x32_bf16(al, bh, acc[nt], 0, 0, 0);
        }
    }
    // score from regs
    #pragma unroll
    for (int r = 0; r < 4; r++){
        float sp = 0.f;
        #pragma unroll
        for (int nt = 0; nt < 8; nt++){
            int c = nt*16 + ln;
            sp += (acc[nt][r] + bsh[c]) * qs[c];
        }
        sp += __shfl_xor(sp, 1);
        sp += __shfl_xor(sp, 2);
        sp += __shfl_xor(sp, 4);
        sp += __shfl_xor(sp, 8);
        if (ln == 0){
            int rl = wave*16 + q*4 + r;
            scs[rl] = sp + b1v * (float)cntv[g*128 + rl];
        }
    }
    __syncthreads();                       // wsh/wsl reads done -> safe to overwrite
    float* Yl = (float*)smem;              // [128][132]
    #pragma unroll
    for (int nt = 0; nt < 8; nt++){
        int c = nt*16 + ln;
        float bb = bsh[c];
        #pragma unroll
        for (int r = 0; r < 4; r++){
            Yl[(wave*16 + q*4 + r)*132 + c] = acc[nt][r] + bb;
        }
    }
    __syncthreads();
    if (t < 128){
        float s = scs[t];
        int rank = 0;
        const float4* sc4 = (const float4*)scs;
        #pragma unroll 8
        for (int j4 = 0; j4 < 32; j4++){
            float4 v = sc4[j4];
            int j = j4*4;
            rank += (v.x > s) || (v.x == s && (j+0) < t);   // stable tie-break = lax.top_k
            rank += (v.y > s) || (v.y == s && (j+1) < t);
            rank += (v.z > s) || (v.z == s && (j+2) < t);
            rank += (v.w > s) || (v.w == s && (j+3) < t);
        }
        if (rank < 64){ selS[rank] = t; thS[rank] = tanhf(s); }
    }
    __syncthreads();
    if (t < 128){
        float s = 0.f;
        #pragma unroll 8
        for (int r = 0; r < 64; r++) s += Yl[selS[r]*132 + t] * thS[r];
        mr[t] = s * (1.f/64.f);
    }
    __syncthreads();
    if (t < 64){
        float a = b1[t];
        #pragma unroll 8
        for (int k = 0; k < 128; k++) a += mr[k]*W1[k*64 + t];
        a = fmaxf(a, 0.f);
        float r = a * W2[t];
        #pragma unroll
        for (int off = 32; off > 0; off >>= 1) r += __shfl_down(r, off);
        if (t == 0) out[g] = r + b2[0];
    }
}

// ---------------- driver: 11 launches ----------------
extern "C" void kernel_launch(void* const* d_in, const int* in_sizes, int n_in,
                              void* d_out, int out_size, void* d_ws, size_t ws_size,
                              hipStream_t stream){
    (void)in_sizes; (void)n_in; (void)out_size; (void)ws_size;
    const float* x     = (const float*)d_in[0];
    const int*   ei    = (const int*)d_in[1];
    const float* lumpW = (const float*)d_in[3];
    const float* lumpb = (const float*)d_in[4];
    const float* convW[3]    = {(const float*)d_in[5], (const float*)d_in[7], (const float*)d_in[9]};
    const float* convB[3]    = {(const float*)d_in[6], (const float*)d_in[8], (const float*)d_in[10]};
    const float* poolP[3]    = {(const float*)d_in[11], (const float*)d_in[13], (const float*)d_in[15]};
    const float* poolBeta[3] = {(const float*)d_in[12], (const float*)d_in[14], (const float*)d_in[16]};
    const float* lin1W = (const float*)d_in[17];
    const float* lin1b = (const float*)d_in[18];
    const float* lin2W = (const float*)d_in[19];
    const float* lin2b = (const float*)d_in[20];
    float* out = (float*)d_out;

    char* w8 = (char*)d_ws;
    size_t off = 0;
    auto alloc = [&](size_t bytes)->char*{
        char* p = w8 + off; off += (bytes + 255) & ~(size_t)255; return p;
    };
    float* A     = (float*)alloc((size_t)65536*128*4);
    float* Bb    = (float*)alloc((size_t)65536*128*4);
    int*   srcA  = (int*)alloc((size_t)E_*4);
    int*   dstA  = (int*)alloc((size_t)E_*4);
    unsigned short* csr1 = (unsigned short*)alloc((size_t)65536*DEGMAX*2);
    unsigned short* csr2 = (unsigned short*)alloc((size_t)32768*DEGMAX*2);
    unsigned short* csr3 = (unsigned short*)alloc((size_t)16384*DEGMAX*2);
    int*   cntA  = (int*)alloc((size_t)(65536+32768+16384)*4);
    int*   cnt1 = cntA, *cnt2 = cntA + 65536, *cnt3 = cntA + 98304;
    int*   perm1 = (int*)alloc((size_t)65536*4);
    int*   perm2 = (int*)alloc((size_t)32768*4);
    int*   perm3 = (int*)alloc((size_t)16384*4);
    float* dinv1 = (float*)alloc((size_t)65536*4);
    float* dinv2 = (float*)alloc((size_t)32768*4);
    float* dinv3 = (float*)alloc((size_t)16384*4);
    float* score1 = (float*)alloc((size_t)65536*4);
    float* score2 = (float*)alloc((size_t)32768*4);
    int*   sel2  = (int*)alloc((size_t)32768*4);
    int*   sel3  = (int*)alloc((size_t)16384*4);
    float* th2   = (float*)alloc((size_t)32768*4);
    float* th3   = (float*)alloc((size_t)16384*4);
    unsigned short* wsp = (unsigned short*)alloc((size_t)4*2*17408*2);
    unsigned short* wspLump = wsp;
    unsigned short* wspC0   = wsp + 1*2*17408;
    unsigned short* wspC1   = wsp + 2*2*17408;
    unsigned short* wspC2   = wsp + 3*2*17408;

    // ----- W pre-split (once), prep1 (LDS CSR build), lump GEMM -----
    k_splitW<<<32, 256, 0, stream>>>(lumpW, convW[0], convW[1], convW[2], wsp);
    k_prep1<<<G_, 512, 0, stream>>>(ei, cnt1, csr1, perm1, dinv1);
    k_gemm_mfma<8><<<512, 512, 0, stream>>>(x, wspLump, lumpb, A,
            nullptr, nullptr, nullptr, nullptr);

    // ----- stage 1: conv1 (L=4, nper=512), pool -> 256/graph -----
    k_prop<512,4,4,false><<<dim3(G_,4), 1024, 0, stream>>>(perm1, dinv1, csr1, A,
            nullptr, nullptr, Bb);
    k_gemm_mfma<8><<<512, 512, 0, stream>>>(Bb, wspC0, convB[0], A,
            poolP[0], poolBeta[0], cnt1, score1);
    k_pooltop<512,true><<<G_, 512, 0, stream>>>(score1, ei, ei + E_, srcA, dstA,
            cnt2, csr2, perm2, dinv2, sel2, th2);

    // ----- stage 2: conv2 (L=2, nper=256), pool -> 128/graph -----
    k_prop<256,2,2,true><<<dim3(G_,4), 1024, 0, stream>>>(perm2, dinv2, csr2, A,
            sel2, th2, Bb);
    k_gemm_mfma<8><<<256, 512, 0, stream>>>(Bb, wspC1, convB[1], A,
            poolP[1], poolBeta[1], cnt2, score2);
    k_pooltop<256,true><<<G_, 512, 0, stream>>>(score2, srcA, dstA, srcA, dstA,
            cnt3, csr3, perm3, dinv3, sel3, th3);

    // ----- stage 3: conv3 (L=2, nper=128) then fused conv3-gemm+pool+mean+MLP -----
    k_prop<128,2,1,true><<<dim3(G_,4), 1024, 0, stream>>>(perm3, dinv3, csr3, A,
            sel3, th3, Bb);
    k_stage3<<<G_, 512, 0, stream>>>(Bb, wspC2, convB[2],
            poolP[2], poolBeta[2], cnt3, lin1W, lin1b, lin2W, lin2b, out);
}